// Round 3
// baseline (169.058 us; speedup 1.0000x reference)
//
#include <hip/hip_runtime.h>
#include <math.h>

// Problem constants
#define B_   64
#define T_   512
#define D_   96
#define TY_  512
#define H_   4
#define DK_  32
#define E_   128
#define P_   2
#define L_   64
#define HID_ 128

// Workspace layout (float offsets)
#define WS_OB2P  1024      // 8*64 : ob2 partials (const-half of ow, 8 slices)
#define WS_PN    2048      // 64b*8c*8hp*96f = 393216 : partial numerators
#define WS_PD    395264    // 393216 : partial denominators

// ---------------------------------------------------------------------------
// Kernel 1 (512 blocks = 8 t-chunks x 64 b, 256 thr): prep + scores + exp +
// masked pooling partials.  (unchanged from round 2 — SQ_LDS_BANK_CONFLICT=0)
// ---------------------------------------------------------------------------
__global__ __launch_bounds__(256) void kphase1(
    const float* __restrict__ tsteps, const float* __restrict__ te_w,
    const float* __restrict__ te_b,   const float* __restrict__ X,
    const float* __restrict__ M,      const float* __restrict__ query,
    const float* __restrict__ q_w,    const float* __restrict__ q_b,
    const float* __restrict__ k_w,    const float* __restrict__ k_b,
    const float* __restrict__ ow,     float* __restrict__ ws)
{
    const int bi = blockIdx.x, tid = threadIdx.x;
    const int c = bi & 7, b = bi >> 3;

    __shared__ float qm[P_ * E_];
    __shared__ float w2q_s[E_ * 8];
    __shared__ float tw_s[E_], tb_s[E_], bq_s[8];
    __shared__ float w_s[8][64];        // [hp][t]
    __shared__ float red[96 * 17];      // stride 17: no bank conflicts
    __shared__ float obp2[4][64];

    // ---- Prologue: fused q/k weights ----
    {
        int p = tid >> 7, ep = tid & 127;
        float acc = q_b[ep];
        #pragma unroll 4
        for (int e = 0; e < E_; ++e)
            acc += query[p * E_ + e] * q_w[e * E_ + ep];
        qm[p * E_ + ep] = acc;
    }
    if (tid < E_) { tw_s[tid] = te_w[tid]; tb_s[tid] = te_b[tid]; }
    __syncthreads();
    const float rs = 0.17677669529663687f;  // 1/sqrt(32)
    #pragma unroll
    for (int i = 0; i < 4; ++i) {
        int idx = tid + i * 256;
        int e = idx >> 3, hp = idx & 7, h = hp >> 1, p = hp & 1;
        float acc = 0.f;
        #pragma unroll
        for (int dk = 0; dk < DK_; ++dk)
            acc += k_w[e * E_ + h * DK_ + dk] * qm[p * E_ + h * DK_ + dk];
        w2q_s[idx] = acc * rs;
    }
    if (tid < 8) {
        int hp = tid, h = hp >> 1, p = hp & 1;
        float acc = 0.f;
        #pragma unroll
        for (int dk = 0; dk < DK_; ++dk)
            acc += k_b[h * DK_ + dk] * qm[p * E_ + h * DK_ + dk];
        bq_s[hp] = acc * rs;
    }
    __syncthreads();

    // ---- Phase A: thread = (t in chunk, hp-pair) ----
    {
        const int t = tid & 63, hpg = tid >> 6, hp0 = hpg * 2;
        const float tv = tsteps[b * T_ + c * 64 + t];
        float a0 = 0.f, a1 = 0.f;
        #pragma unroll 4
        for (int e = 0; e < E_; ++e) {
            float v = tv * tw_s[e] + tb_s[e];
            if ((e & 3) == 0) v = __sinf(v);
            float2 w = *(const float2*)&w2q_s[e * 8 + hp0];
            a0 += v * w.x;
            a1 += v * w.y;
        }
        w_s[hp0][t]     = __expf(a0 + bq_s[hp0]);       // lanes: consecutive t
        w_s[hp0 + 1][t] = __expf(a1 + bq_s[hp0 + 1]);   // -> conflict-free
    }
    __syncthreads();

    // ---- Phase B: 2 t-slices x 128 fid (96 active) ----
    const int fid = tid & 127, slice = tid >> 7;
    float num[8] = {0.f, 0.f, 0.f, 0.f, 0.f, 0.f, 0.f, 0.f};
    float den[8] = {0.f, 0.f, 0.f, 0.f, 0.f, 0.f, 0.f, 0.f};
    if (fid < 96) {
        #pragma unroll 4
        for (int i = 0; i < 32; ++i) {
            int tl = slice + 2 * i;           // wave-uniform
            size_t base = ((size_t)(b * T_ + c * 64 + tl)) * D_ + fid;
            float m = M[base], x = X[base];
            float mx = m * x;
            #pragma unroll
            for (int hp = 0; hp < 8; ++hp) {  // w_s[hp][tl]: LDS broadcast
                num[hp] += w_s[hp][tl] * mx;
                den[hp] += w_s[hp][tl] * m;
            }
        }
    }
    __syncthreads();
    if (slice == 1 && fid < 96) {
        #pragma unroll
        for (int hp = 0; hp < 8; ++hp) {
            red[fid * 17 + hp]     = num[hp];
            red[fid * 17 + 8 + hp] = den[hp];
        }
    }
    __syncthreads();
    if (slice == 0 && fid < 96) {
        float* pN = ws + WS_PN + ((size_t)((b * 8 + c) * 8)) * 96;
        float* pD = ws + WS_PD + ((size_t)((b * 8 + c) * 8)) * 96;
        #pragma unroll
        for (int hp = 0; hp < 8; ++hp) {
            pN[hp * 96 + fid] = num[hp] + red[fid * 17 + hp];
            pD[hp * 96 + fid] = den[hp] + red[fid * 17 + 8 + hp];
        }
    }

    // ---- Epilogue (b==0 only): ob2 partial slice c over 48 (h,j) pairs ----
    if (b == 0) {
        int sub = tid >> 6, l = tid & 63;
        float acc = 0.f;
        #pragma unroll
        for (int k = 0; k < 12; ++k) {
            int hj = c * 48 + sub * 12 + k;
            int h = hj / 96, j = hj - h * 96;
            acc += ow[(size_t)(h * 2 * D_ + D_ + j) * L_ + l];
        }
        obp2[sub][l] = acc;
        __syncthreads();
        if (sub == 0)
            ws[WS_OB2P + c * 64 + l] = obp2[0][l] + obp2[1][l]
                                     + obp2[2][l] + obp2[3][l];
    }
}

// ---------------------------------------------------------------------------
// Kernel 2 (512 blocks, 256 thr): partials -> xa -> coeffs -> a0/a1
// (redundant x8 per b, L2-hot) then the decoder GEMM for the block's 64
// output positions.
//
// Decoder re-tile (round-3 change): thread = (pg = tid>>4 owns 4 positions,
// ds = tid&15 owns 6 columns). Per j a thread reads only 6 w2 floats
// (3x ds_read_b64; per wave 16 distinct addresses at banks 6k mod 32 — all
// distinct -> conflict-free, 4-way broadcast) + one b64 for the interleaved
// (a0,a1) pair, and runs 24 FMA + 4 h-FMA + 4 max. That is ~16 LDS-cy per
// j per wave vs ~52 for the old (pos, 24-col) tiling — the old loop was
// LDS-throughput-bound at 4 B/FMA (22 us of pure LDS issue per CU).
// Stores: 16 lanes of common pg write one contiguous 384 B row -> full
// 64 B lines (old layout wrote 96 B per 384 B per wave -> WRITE_SIZE 3x).
// ---------------------------------------------------------------------------
__global__ __launch_bounds__(256) void kphase2(
    const float* __restrict__ ow, const float* __restrict__ ob,
    const float* __restrict__ w1, const float* __restrict__ b1,
    const float* __restrict__ yts, const float* __restrict__ w2,
    const float* __restrict__ b2, const float* __restrict__ ws,
    float* __restrict__ out)
{
    __shared__ float w2_s[HID_ * D_];   // 48 KB, [j][96]
    __shared__ float xa_s[8 * 96];
    __shared__ float cfp[4][2][64];
    __shared__ float cf_s[2][64];
    __shared__ float ab_s[HID_][2];     // interleaved (a0,a1): one b64/j
    __shared__ float y_s[64];
    __shared__ float abp[2][2][128];

    const int bi = blockIdx.x, tid = threadIdx.x;
    const int b = bi >> 3;

    // issue w2 prefetch (12 x float4/thread, coalesced) — consumed at (f)
    float4 wreg[12];
    {
        const float4* src = (const float4*)w2;
        #pragma unroll
        for (int i = 0; i < 12; ++i) wreg[i] = src[tid + i * 256];
    }
    if (tid < 64) y_s[tid] = yts[bi * 64 + tid];

    // (a) reduce pool partials -> xa
    #pragma unroll
    for (int it = 0; it < 3; ++it) {
        int flat = tid + it * 256;
        int hp = flat / 96, f = flat - hp * 96;
        float n = 0.f, d = 0.f;
        #pragma unroll
        for (int cc = 0; cc < 8; ++cc) {
            n += ws[WS_PN + ((size_t)((b * 8 + cc) * 8 + hp)) * 96 + f];
            d += ws[WS_PD + ((size_t)((b * 8 + cc) * 8 + hp)) * 96 + f];
        }
        xa_s[flat] = n / d;
    }
    __syncthreads();

    // (b) coeff GEMV, 2 items/thread over (h,p,l); lanes span l -> each f
    // step reads a contiguous 256 B row of ow (coalesced, L2-hot)
    #pragma unroll
    for (int it = 0; it < 2; ++it) {
        int idx = tid + it * 256;
        int h = idx >> 7, p = (idx >> 6) & 1, l = idx & 63;
        const float* xr = xa_s + (h * 2 + p) * 96;
        const float* owr = ow + (size_t)(h * 2 * D_) * L_ + l;
        float acc = 0.f;
        #pragma unroll 4
        for (int f = 0; f < 96; ++f)
            acc += xr[f] * owr[(size_t)f * L_];
        cfp[h][p][l] = acc;
    }
    __syncthreads();

    // (c) combine coeff partials + ob + ob2 partials
    if (tid < 128) {
        int p = tid >> 6, l = tid & 63;
        float v = cfp[0][p][l] + cfp[1][p][l] + cfp[2][p][l]
                + cfp[3][p][l] + ob[l];
        #pragma unroll
        for (int g = 0; g < 8; ++g) v += ws[WS_OB2P + g * 64 + l];
        cf_s[p][l] = v;
    }
    __syncthreads();

    // (d) a0/a1 GEMV, thread = (l-slice, j)
    {
        int s = tid >> 7, j = tid & 127;
        float a0 = 0.f, a1 = 0.f;
        #pragma unroll 4
        for (int li = 0; li < 32; ++li) {
            int l = s * 32 + li;
            float wv = w1[l * HID_ + j];
            a0 += cf_s[0][l] * wv;
            a1 += cf_s[1][l] * wv;
        }
        abp[s][0][j] = a0;
        abp[s][1][j] = a1;
    }
    __syncthreads();

    // (e) combine a0/a1 (interleaved) + (f) land w2 prefetch in LDS
    if (tid < 128) {
        ab_s[tid][0] = abp[0][0][tid] + abp[1][0][tid] + b1[tid];
    } else {
        int j = tid - 128;
        ab_s[j][1] = abp[0][1][j] + abp[1][1][j];
    }
    {
        float4* dst = (float4*)w2_s;
        #pragma unroll
        for (int i = 0; i < 12; ++i) dst[tid + i * 256] = wreg[i];
    }
    __syncthreads();

    // (g) decoder: thread = (pg = tid>>4: 4 positions, ds = tid&15: 6 cols)
    const int pg = tid >> 4, ds = tid & 15;
    const int d0 = ds * 6;

    float yv[4];
    #pragma unroll
    for (int p = 0; p < 4; ++p) yv[p] = y_s[pg * 4 + p];

    float acc[4][6];
    #pragma unroll
    for (int p = 0; p < 4; ++p)
        #pragma unroll
        for (int q = 0; q < 6; ++q) acc[p][q] = 0.f;

    #pragma unroll 4
    for (int j = 0; j < HID_; ++j) {
        float2 ab = *(const float2*)&ab_s[j][0];     // wave-uniform b64
        float h[4];
        #pragma unroll
        for (int p = 0; p < 4; ++p)
            h[p] = fmaxf(0.f, ab.x + yv[p] * ab.y);
        const float* wr = w2_s + j * D_ + d0;        // 3x b64, conflict-free
        float2 wa = *(const float2*)(wr);
        float2 wb = *(const float2*)(wr + 2);
        float2 wc = *(const float2*)(wr + 4);
        #pragma unroll
        for (int p = 0; p < 4; ++p) {
            acc[p][0] += h[p] * wa.x;
            acc[p][1] += h[p] * wa.y;
            acc[p][2] += h[p] * wb.x;
            acc[p][3] += h[p] * wb.y;
            acc[p][4] += h[p] * wc.x;
            acc[p][5] += h[p] * wc.y;
        }
    }

    // epilogue: bias + store. 16 lanes (common pg) cover one row's 384 B
    // contiguously -> full-line writes.
    float bb[6];
    #pragma unroll
    for (int q = 0; q < 6; ++q) bb[q] = b2[d0 + q];
    #pragma unroll
    for (int p = 0; p < 4; ++p) {
        float* op = out + ((size_t)(bi * 64 + pg * 4 + p)) * D_ + d0;
        #pragma unroll
        for (int q = 0; q < 3; ++q) {
            float2 v;
            v.x = acc[p][2 * q]     + bb[2 * q];
            v.y = acc[p][2 * q + 1] + bb[2 * q + 1];
            *(float2*)(op + 2 * q) = v;
        }
    }
}

// ---------------------------------------------------------------------------
extern "C" void kernel_launch(void* const* d_in, const int* in_sizes, int n_in,
                              void* d_out, int out_size, void* d_ws, size_t ws_size,
                              hipStream_t stream)
{
    const float* timesteps = (const float*)d_in[0];
    const float* X         = (const float*)d_in[1];
    const float* M         = (const float*)d_in[2];
    const float* yts       = (const float*)d_in[3];
    const float* te_w      = (const float*)d_in[4];
    const float* te_b      = (const float*)d_in[5];
    const float* query     = (const float*)d_in[6];
    const float* q_w       = (const float*)d_in[7];
    const float* q_b       = (const float*)d_in[8];
    const float* k_w       = (const float*)d_in[9];
    const float* k_b       = (const float*)d_in[10];
    const float* ow        = (const float*)d_in[11];
    const float* ob        = (const float*)d_in[12];
    const float* w1        = (const float*)d_in[13];
    const float* b1        = (const float*)d_in[14];
    const float* w2        = (const float*)d_in[15];
    const float* b2        = (const float*)d_in[16];
    float* out = (float*)d_out;
    float* ws  = (float*)d_ws;

    kphase1<<<512, 256, 0, stream>>>(timesteps, te_w, te_b, X, M, query,
                                     q_w, q_b, k_w, k_b, ow, ws);
    kphase2<<<512, 256, 0, stream>>>(ow, ob, w1, b1, yts, w2, b2, ws, out);
}

// Round 4
// 165.575 us; speedup vs baseline: 1.0210x; 1.0210x over previous
//
#include <hip/hip_runtime.h>
#include <math.h>

// Problem constants
#define B_   64
#define T_   512
#define D_   96
#define TY_  512
#define H_   4
#define DK_  32
#define E_   128
#define P_   2
#define L_   64
#define HID_ 128

// Workspace layout (float offsets)
#define WS_OB2P  1024      // 8*64 : ob2 partials (const-half of ow, 8 slices)
#define WS_PN    2048      // 64b*8c*8hp*96f = 393216 : partial numerators
#define WS_PD    395264    // 393216 : partial denominators
// Piecewise-linear decoder tables: per-b region of RSZ_ floats at WS_TAB.
//   [0..128)       : sorted thresholds (padded +INF)
//   [256..256+129*192) : rows k=0..128, each {R0[96] | R1[96]}
#define WS_TAB   1048576
#define RSZ_     25088
#define TABOFF   256

// ---------------------------------------------------------------------------
// Kernel 1 (512 blocks = 8 t-chunks x 64 b, 256 thr): prep + scores + exp +
// masked pooling partials. Round-4 tweak: w LDS tile stored [t][8] so Phase-B
// reads are 2x ds_read_b128 broadcasts per t (was 8x b32). Phase-A writes are
// only 2 instrs/thread, so their bank conflicts are negligible.
// ---------------------------------------------------------------------------
__global__ __launch_bounds__(256) void kphase1(
    const float* __restrict__ tsteps, const float* __restrict__ te_w,
    const float* __restrict__ te_b,   const float* __restrict__ X,
    const float* __restrict__ M,      const float* __restrict__ query,
    const float* __restrict__ q_w,    const float* __restrict__ q_b,
    const float* __restrict__ k_w,    const float* __restrict__ k_b,
    const float* __restrict__ ow,     float* __restrict__ ws)
{
    const int bi = blockIdx.x, tid = threadIdx.x;
    const int c = bi & 7, b = bi >> 3;

    __shared__ float qm[P_ * E_];
    __shared__ float w2q_s[E_ * 8];
    __shared__ float tw_s[E_], tb_s[E_], bq_s[8];
    __shared__ float w_sB[64][8];       // [t][hp]
    __shared__ float red[96 * 17];      // stride 17: no bank conflicts
    __shared__ float obp2[4][64];

    // ---- Prologue: fused q/k weights ----
    {
        int p = tid >> 7, ep = tid & 127;
        float acc = q_b[ep];
        #pragma unroll 4
        for (int e = 0; e < E_; ++e)
            acc += query[p * E_ + e] * q_w[e * E_ + ep];
        qm[p * E_ + ep] = acc;
    }
    if (tid < E_) { tw_s[tid] = te_w[tid]; tb_s[tid] = te_b[tid]; }
    __syncthreads();
    const float rs = 0.17677669529663687f;  // 1/sqrt(32)
    #pragma unroll
    for (int i = 0; i < 4; ++i) {
        int idx = tid + i * 256;
        int e = idx >> 3, hp = idx & 7, h = hp >> 1, p = hp & 1;
        float acc = 0.f;
        #pragma unroll
        for (int dk = 0; dk < DK_; ++dk)
            acc += k_w[e * E_ + h * DK_ + dk] * qm[p * E_ + h * DK_ + dk];
        w2q_s[idx] = acc * rs;
    }
    if (tid < 8) {
        int hp = tid, h = hp >> 1, p = hp & 1;
        float acc = 0.f;
        #pragma unroll
        for (int dk = 0; dk < DK_; ++dk)
            acc += k_b[h * DK_ + dk] * qm[p * E_ + h * DK_ + dk];
        bq_s[hp] = acc * rs;
    }
    __syncthreads();

    // ---- Phase A: thread = (t in chunk, hp-pair) ----
    {
        const int t = tid & 63, hpg = tid >> 6, hp0 = hpg * 2;
        const float tv = tsteps[b * T_ + c * 64 + t];
        float a0 = 0.f, a1 = 0.f;
        #pragma unroll 4
        for (int e = 0; e < E_; ++e) {
            float v = tv * tw_s[e] + tb_s[e];
            if ((e & 3) == 0) v = __sinf(v);
            float2 w = *(const float2*)&w2q_s[e * 8 + hp0];
            a0 += v * w.x;
            a1 += v * w.y;
        }
        float e0 = __expf(a0 + bq_s[hp0]);
        float e1 = __expf(a1 + bq_s[hp0 + 1]);
        *(float2*)&w_sB[t][hp0] = make_float2(e0, e1);
    }
    __syncthreads();

    // ---- Phase B: 2 t-slices x 128 fid (96 active) ----
    const int fid = tid & 127, slice = tid >> 7;
    float num[8] = {0.f, 0.f, 0.f, 0.f, 0.f, 0.f, 0.f, 0.f};
    float den[8] = {0.f, 0.f, 0.f, 0.f, 0.f, 0.f, 0.f, 0.f};
    if (fid < 96) {
        #pragma unroll 4
        for (int i = 0; i < 32; ++i) {
            int tl = slice + 2 * i;           // wave-uniform
            size_t base = ((size_t)(b * T_ + c * 64 + tl)) * D_ + fid;
            float m = M[base], x = X[base];
            float mx = m * x;
            float4 wa = *(const float4*)&w_sB[tl][0];   // b128 broadcast
            float4 wb = *(const float4*)&w_sB[tl][4];
            float wv[8];
            *(float4*)&wv[0] = wa; *(float4*)&wv[4] = wb;
            #pragma unroll
            for (int hp = 0; hp < 8; ++hp) {
                num[hp] += wv[hp] * mx;
                den[hp] += wv[hp] * m;
            }
        }
    }
    __syncthreads();
    if (slice == 1 && fid < 96) {
        #pragma unroll
        for (int hp = 0; hp < 8; ++hp) {
            red[fid * 17 + hp]     = num[hp];
            red[fid * 17 + 8 + hp] = den[hp];
        }
    }
    __syncthreads();
    if (slice == 0 && fid < 96) {
        float* pN = ws + WS_PN + ((size_t)((b * 8 + c) * 8)) * 96;
        float* pD = ws + WS_PD + ((size_t)((b * 8 + c) * 8)) * 96;
        #pragma unroll
        for (int hp = 0; hp < 8; ++hp) {
            pN[hp * 96 + fid] = num[hp] + red[fid * 17 + hp];
            pD[hp * 96 + fid] = den[hp] + red[fid * 17 + 8 + hp];
        }
    }

    // ---- Epilogue (b==0 only): ob2 partial slice c over 48 (h,j) pairs ----
    if (b == 0) {
        int sub = tid >> 6, l = tid & 63;
        float acc = 0.f;
        #pragma unroll
        for (int k = 0; k < 12; ++k) {
            int hj = c * 48 + sub * 12 + k;
            int h = hj / 96, j = hj - h * 96;
            acc += ow[(size_t)(h * 2 * D_ + D_ + j) * L_ + l];
        }
        obp2[sub][l] = acc;
        __syncthreads();
        if (sub == 0)
            ws[WS_OB2P + c * 64 + l] = obp2[0][l] + obp2[1][l]
                                     + obp2[2][l] + obp2[3][l];
    }
}

// ---------------------------------------------------------------------------
// Kernel AB (64 blocks x 256 thr): partials -> xa -> coeffs -> (a0,a1), then
// build the piecewise-linear decoder tables.
//
// out[pos,d] = sum_j relu(a0_j + y*a1_j) w2[j,d] + b2[d] is piecewise-linear
// in y. With relu(x) = (x+|x|)/2 and |a0+y*a1| = |a1|*|y - t_j|,
// t_j = -a0/a1, u_j = |a1_j|, vt_j = u_j*t_j = -a0_j*sgn(a1_j) (bounded even
// for tiny a1):
//   out(y,d) = R0(k,d) + y*R1(k,d),  k = #{ t_j < y }
//   R0(k) = 0.5*(G0 + C + Vtot) + b2 - V(k)
//   R1(k) = 0.5*(G1 - Utot) + U(k)
// where G0/G1 = sum a0/a1*w2 (all j), C = sum_{a1==0} |a0|*w2,
// U(k)/V(k) = prefix sums of u/vt*w2 in threshold-sorted order.
// Tables: 129 rows x {R0[96]|R1[96]} per b -> ws. Exact algebra; only the
// summation order changes (fp error ~1e-5 << 0.0078 tolerance).
// ---------------------------------------------------------------------------
__global__ __launch_bounds__(256) void kab(
    const float* __restrict__ ow, const float* __restrict__ ob,
    const float* __restrict__ w1, const float* __restrict__ b1,
    const float* __restrict__ w2, const float* __restrict__ b2,
    float* __restrict__ ws)
{
    __shared__ float w2_s[HID_ * D_];   // 48 KB, [j][d]
    __shared__ float xa_s[8 * 96];
    __shared__ float cfp[4][2][64];
    __shared__ float cf_s[2][64];
    __shared__ float abp[2][2][128];
    __shared__ float ab0_s[HID_], ab1_s[HID_];
    __shared__ float t_s[HID_], u_s[HID_], vt_s[HID_], c0_s[HID_];
    __shared__ int   sidx_s[HID_];
    __shared__ float base0_s[96], base1_s[96];

    const int b = blockIdx.x, tid = threadIdx.x;

    // stage w2 (12288 floats, coalesced)
    {
        const float4* src = (const float4*)w2;
        float4* dst = (float4*)w2_s;
        #pragma unroll
        for (int i = 0; i < 12; ++i) dst[tid + i * 256] = src[tid + i * 256];
    }

    // (a) reduce pool partials -> xa (once per b)
    #pragma unroll
    for (int it = 0; it < 3; ++it) {
        int flat = tid + it * 256;
        int hp = flat / 96, f = flat - hp * 96;
        float n = 0.f, d = 0.f;
        #pragma unroll
        for (int cc = 0; cc < 8; ++cc) {
            n += ws[WS_PN + ((size_t)((b * 8 + cc) * 8 + hp)) * 96 + f];
            d += ws[WS_PD + ((size_t)((b * 8 + cc) * 8 + hp)) * 96 + f];
        }
        xa_s[flat] = n / d;
    }
    __syncthreads();

    // (b) coeff GEMV
    #pragma unroll
    for (int it = 0; it < 2; ++it) {
        int idx = tid + it * 256;
        int h = idx >> 7, p = (idx >> 6) & 1, l = idx & 63;
        const float* xr = xa_s + (h * 2 + p) * 96;
        const float* owr = ow + (size_t)(h * 2 * D_) * L_ + l;
        float acc = 0.f;
        #pragma unroll 4
        for (int f = 0; f < 96; ++f)
            acc += xr[f] * owr[(size_t)f * L_];
        cfp[h][p][l] = acc;
    }
    __syncthreads();

    // (c) combine coeff partials + ob + ob2 partials
    if (tid < 128) {
        int p = tid >> 6, l = tid & 63;
        float v = cfp[0][p][l] + cfp[1][p][l] + cfp[2][p][l]
                + cfp[3][p][l] + ob[l];
        #pragma unroll
        for (int g = 0; g < 8; ++g) v += ws[WS_OB2P + g * 64 + l];
        cf_s[p][l] = v;
    }
    __syncthreads();

    // (d) a0/a1 GEMV
    {
        int s = tid >> 7, j = tid & 127;
        float a0 = 0.f, a1 = 0.f;
        #pragma unroll 4
        for (int li = 0; li < 32; ++li) {
            int l = s * 32 + li;
            float wv = w1[l * HID_ + j];
            a0 += cf_s[0][l] * wv;
            a1 += cf_s[1][l] * wv;
        }
        abp[s][0][j] = a0;
        abp[s][1][j] = a1;
    }
    __syncthreads();

    // (e) combine
    if (tid < 128) {
        ab0_s[tid] = abp[0][0][tid] + abp[1][0][tid] + b1[tid];
    } else {
        int j = tid - 128;
        ab1_s[j] = abp[0][1][j] + abp[1][1][j];
    }
    __syncthreads();

    // (f) classify: threshold / u / vt / zero-slope constant
    if (tid < 128) {
        float a0 = ab0_s[tid], a1 = ab1_s[tid];
        float t, u, vt, c0;
        if (a1 > 0.f)      { t = -a0 / a1;  u =  a1; vt = -a0; c0 = 0.f; }
        else if (a1 < 0.f) { t = -a0 / a1;  u = -a1; vt =  a0; c0 = 0.f; }
        else               { t = INFINITY;  u = 0.f; vt = 0.f; c0 = fabsf(a0); }
        t_s[tid] = t; u_s[tid] = u; vt_s[tid] = vt; c0_s[tid] = c0;
    }
    __syncthreads();

    // (g) rank sort (O(128^2), strict total order via index tiebreak)
    if (tid < 128) {
        float tj = t_s[tid];
        int r = 0;
        for (int k = 0; k < 128; ++k) {
            float tk = t_s[k];
            r += (tk < tj) || (tk == tj && k < tid);
        }
        sidx_s[r] = tid;
    }
    __syncthreads();

    // (h) fused 5-GEMV (G0,G1,Utot,Vtot,C) -> bases; lanes>=128 write the
    // sorted thresholds to ws in parallel.
    float* reg = ws + WS_TAB + (size_t)b * RSZ_;
    if (tid < 96) {
        float g0 = 0.f, g1 = 0.f, ut = 0.f, vta = 0.f, cc2 = 0.f;
        #pragma unroll 4
        for (int j = 0; j < 128; ++j) {
            float wv = w2_s[j * 96 + tid];
            g0  += ab0_s[j] * wv;
            g1  += ab1_s[j] * wv;
            ut  += u_s[j]  * wv;
            vta += vt_s[j] * wv;
            cc2 += c0_s[j] * wv;
        }
        base0_s[tid] = 0.5f * (g0 + cc2 + vta) + b2[tid];
        base1_s[tid] = 0.5f * (g1 - ut);
    } else if (tid >= 128) {
        int k = tid - 128;
        reg[k] = t_s[sidx_s[k]];
    }
    __syncthreads();

    // (i) prefix build: row k -> {R0|R1}; coalesced 384 B stores per row half
    if (tid < 96) {
        float cur0 = base0_s[tid], cur1 = base1_s[tid];
        float* tb = reg + TABOFF;
        tb[tid] = cur0;
        tb[96 + tid] = cur1;
        #pragma unroll 4
        for (int k = 0; k < 128; ++k) {
            int j = sidx_s[k];
            float wv = w2_s[j * 96 + tid];
            cur0 -= vt_s[j] * wv;
            cur1 += u_s[j] * wv;
            tb[(k + 1) * 192 + tid]      = cur0;
            tb[(k + 1) * 192 + 96 + tid] = cur1;
        }
    }
}

// ---------------------------------------------------------------------------
// Kernel D (1024 blocks x 256 thr, 32 pos each): binary-search + 2-row read.
// Thread = (pos = tid>>3, dg = tid&7 -> 12 output floats). Tiny LDS ->
// 4 blocks/CU, fully latency-hidden; traffic = ~25 MB table reads (L2/L3)
// + 12.6 MB coalesced output writes.
// ---------------------------------------------------------------------------
__global__ __launch_bounds__(256) void kdec(
    const float* __restrict__ yts, const float* __restrict__ ws,
    float* __restrict__ out)
{
    __shared__ float tS[128];
    const int bi = blockIdx.x, tid = threadIdx.x;
    const int b = bi >> 4;                      // 16 blocks per b
    const float* reg = ws + WS_TAB + (size_t)b * RSZ_;
    if (tid < 128) tS[tid] = reg[tid];
    __syncthreads();

    const int pos = tid >> 3, d0 = (tid & 7) * 12;
    const float y = yts[bi * 32 + pos];

    int lo = 0, hi = 128;
    #pragma unroll
    for (int s = 0; s < 7; ++s) {
        int mid = (lo + hi) >> 1;
        if (tS[mid] < y) lo = mid + 1; else hi = mid;
    }

    const float* R = reg + TABOFF + lo * 192 + d0;
    float* op = out + ((size_t)(bi * 32 + pos)) * D_ + d0;
    #pragma unroll
    for (int q = 0; q < 3; ++q) {
        float4 r0 = *(const float4*)(R + q * 4);
        float4 r1 = *(const float4*)(R + 96 + q * 4);
        float4 v;
        v.x = r0.x + y * r1.x;
        v.y = r0.y + y * r1.y;
        v.z = r0.z + y * r1.z;
        v.w = r0.w + y * r1.w;
        *(float4*)(op + q * 4) = v;
    }
}

// ---------------------------------------------------------------------------
extern "C" void kernel_launch(void* const* d_in, const int* in_sizes, int n_in,
                              void* d_out, int out_size, void* d_ws, size_t ws_size,
                              hipStream_t stream)
{
    const float* timesteps = (const float*)d_in[0];
    const float* X         = (const float*)d_in[1];
    const float* M         = (const float*)d_in[2];
    const float* yts       = (const float*)d_in[3];
    const float* te_w      = (const float*)d_in[4];
    const float* te_b      = (const float*)d_in[5];
    const float* query     = (const float*)d_in[6];
    const float* q_w       = (const float*)d_in[7];
    const float* q_b       = (const float*)d_in[8];
    const float* k_w       = (const float*)d_in[9];
    const float* k_b       = (const float*)d_in[10];
    const float* ow        = (const float*)d_in[11];
    const float* ob        = (const float*)d_in[12];
    const float* w1        = (const float*)d_in[13];
    const float* b1        = (const float*)d_in[14];
    const float* w2        = (const float*)d_in[15];
    const float* b2        = (const float*)d_in[16];
    float* out = (float*)d_out;
    float* ws  = (float*)d_ws;

    kphase1<<<512, 256, 0, stream>>>(timesteps, te_w, te_b, X, M, query,
                                     q_w, q_b, k_w, k_b, ow, ws);
    kab<<<B_, 256, 0, stream>>>(ow, ob, w1, b1, w2, b2, ws);
    kdec<<<(B_ * TY_) / 32, 256, 0, stream>>>(yts, ws, out);
}